// Round 5
// baseline (326.973 us; speedup 1.0000x reference)
//
#include <hip/hip_runtime.h>

#define DEVI __device__ __forceinline__

typedef __attribute__((ext_vector_type(8))) short bf16x8;
typedef __attribute__((ext_vector_type(4))) short bf16x4;
typedef __attribute__((ext_vector_type(4))) float f32x4;

#define MFMA16 __builtin_amdgcn_mfma_f32_16x16x32_bf16

// counted waits + raw barrier (used in k_proj / k_denom only)
#define ASM_WAIT_VM_LGKM(n) asm volatile("s_waitcnt vmcnt(" #n ") lgkmcnt(0)" ::: "memory")
#define ASM_WAIT_LGKM() asm volatile("s_waitcnt lgkmcnt(0)" ::: "memory")
#define ASM_BARRIER() do { __builtin_amdgcn_s_barrier(); asm volatile("" ::: "memory"); } while (0)

DEVI short f2bs(float f) {  // fp32 -> bf16 bits, round-nearest-even
  union { float f; unsigned u; } v; v.f = f;
  unsigned r = v.u + 0x7fffu + ((v.u >> 16) & 1u);
  return (short)(r >> 16);
}
DEVI float bs2f(short s) {
  union { unsigned u; float f; } v; v.u = ((unsigned)(unsigned short)s) << 16;
  return v.f;
}

DEVI void gload_lds16(const short* g, short* lds) {
  __builtin_amdgcn_global_load_lds(
      (const __attribute__((address_space(1))) unsigned int*)g,
      (__attribute__((address_space(3))) unsigned int*)lds, 16, 0, 0);
}

// Staged tile layout: [row][32 shorts], 16B-granule XOR-swizzled: physical
// granule gp of row holds logical granule gp ^ ((row>>1)&3).  LDS dest stays
// linear (global_load_lds constraint); the GLOBAL source is inverse-permuted.
// Readers of logical granule q use physical q ^ ((row>>1)&3); for fragment
// reads (row = base16 + col) this folds to the per-lane constant (col>>1)&3.

// stage a [128 rows][32 k] bf16 chunk (8 KB). 2 instrs/thread (256 thr).
DEVI void stage_chunk(short* lds, const short* g, int ldg, int tid) {
#pragma unroll
  for (int it = 0; it < 2; ++it) {
    int slot = it * 256 + tid;          // 0..511
    int row  = slot >> 2;               // 4 granules per 64 B row
    int ko   = ((slot ^ (slot >> 3)) & 3) << 3;   // (g ^ ((row>>1)&3)) * 8
    gload_lds16(g + (size_t)row * ldg + ko, lds + slot * 8);
  }
}

// stage a [64 rows][32 k] bf16 chunk (4 KB). 1 instr/thread (256 thr).
DEVI void stage_chunk64(short* lds, const short* g, int ldg, int tid) {
  int row = tid >> 2;
  int ko  = ((tid ^ (tid >> 3)) & 3) << 3;
  gload_lds16(g + (size_t)row * ldg + ko, lds + tid * 8);
}

// stage phi [32 j][128 k] as 4 chunks of [32][32] (chunk stride 1024 shorts), ldg=128
DEVI void stage_phi32(short* lds, const short* g, int tid) {
#pragma unroll
  for (int it = 0; it < 2; ++it) {
    int slot = it * 256 + tid;          // 0..511
    int ck = slot >> 7;
    int s  = slot & 127;
    int row = s >> 2;                   // 0..31
    int ko  = ((s ^ (s >> 3)) & 3) << 3;
    gload_lds16(g + ck * 32 + (size_t)row * 128 + ko, lds + ck * 1024 + s * 8);
  }
}

DEVI bf16x8 lds8(const short* p) { return *(const bf16x8*)p; }

DEVI void zero_acc(f32x4 (&a)[4][4]) {
  f32x4 z = {0.f, 0.f, 0.f, 0.f};
#pragma unroll
  for (int i = 0; i < 4; ++i)
#pragma unroll
    for (int j = 0; j < 4; ++j) a[i][j] = z;
}

// ---------------- K0: x [b][256][4096] fp32 -> xt [b][4096][256] bf16 ----------------
__global__ __launch_bounds__(256) void k_transpose_cast(const float* __restrict__ x,
                                                        short* __restrict__ xt) {
  __shared__ float t[64][65];
  int b = blockIdx.z;
  int c0 = blockIdx.y * 64;
  int p0 = blockIdx.x * 64;
  int tid = threadIdx.x;
  const float* xb = x + (size_t)b * 256 * 4096;
#pragma unroll
  for (int i = 0; i < 16; ++i) {
    int idx = i * 256 + tid;
    int c = idx >> 6, p = idx & 63;
    t[p][c] = xb[(size_t)(c0 + c) * 4096 + p0 + p];
  }
  __syncthreads();
  short* xtb = xt + ((size_t)b * 4096 + p0) * 256 + c0;
#pragma unroll
  for (int i = 0; i < 16; ++i) {
    int idx = i * 256 + tid;
    int p = idx >> 6, c = idx & 63;
    xtb[(size_t)p * 256 + c] = f2bs(t[p][c]);
  }
}

// ---------------- K0b: cast w1/w2/w3 to bf16 (concatenated [384][256]) ----------------
__global__ __launch_bounds__(256) void k_cast_w(const float* __restrict__ w1,
                                                const float* __restrict__ w2,
                                                const float* __restrict__ w3,
                                                short* __restrict__ w123) {
  int i = blockIdx.x * 256 + threadIdx.x;
  if (i < 384 * 256) {
    int r = i >> 8;
    const float* w = (r < 128) ? w1 : (r < 256 ? w2 : w3);
    w123[i] = f2bs(w[(size_t)(r & 127) * 256 + (i & 255)]);
  }
}

// ---------------- K1: projections. D[pix][ch] = xt . W^T + bias ----------------
__global__ __launch_bounds__(256) void k_proj(const short* __restrict__ xt,
                                              const short* __restrict__ w123,
                                              const float* __restrict__ b1,
                                              const float* __restrict__ b2,
                                              const float* __restrict__ b3,
                                              short* __restrict__ theta,
                                              short* __restrict__ phi,
                                              short* __restrict__ gbuf) {
  __shared__ short aL[2][4096];
  __shared__ short bL[2][4096];
  __shared__ short oL[128 * 136];
  int tid = threadIdx.x;
  int m0 = blockIdx.x * 128;   // pixel tile
  int nb = blockIdx.y;         // 0=theta 1=phi 2=g
  int b  = blockIdx.z;
  int lane = tid & 63, wid = tid >> 6;
  int col = lane & 15, quad = lane >> 4;
  int sl = (col >> 1) & 3;
  int qs = (quad ^ sl) << 3;   // swizzled granule offset (shorts)
  int wm = (wid >> 1) * 64, wn = (wid & 1) * 64;
  const short* A = xt + ((size_t)b * 4096 + m0) * 256;
  const short* B = w123 + (size_t)nb * 128 * 256;
  f32x4 acc[4][4];
  zero_acc(acc);
  // prologue: stage ks=0
  stage_chunk(&aL[0][0], A, 256, tid);
  stage_chunk(&bL[0][0], B, 256, tid);
  for (int ks = 0; ks < 8; ++ks) {
    int cur = ks & 1;
    ASM_WAIT_VM_LGKM(0);    // stage(ks) landed (only outstanding VMEM)
    ASM_BARRIER();
    if (ks < 7) {
      stage_chunk(&aL[cur ^ 1][0], A + (ks + 1) * 32, 256, tid);
      stage_chunk(&bL[cur ^ 1][0], B + (ks + 1) * 32, 256, tid);
    }
    bf16x8 af[4], bf_[4];
#pragma unroll
    for (int mi = 0; mi < 4; ++mi) af[mi] = lds8(&aL[cur][(wm + mi * 16 + col) * 32 + qs]);
#pragma unroll
    for (int ni = 0; ni < 4; ++ni) bf_[ni] = lds8(&bL[cur][(wn + ni * 16 + col) * 32 + qs]);
    __builtin_amdgcn_s_setprio(1);
#pragma unroll
    for (int mi = 0; mi < 4; ++mi)
#pragma unroll
      for (int ni = 0; ni < 4; ++ni)
        acc[mi][ni] = MFMA16(af[mi], bf_[ni], acc[mi][ni], 0, 0, 0);
    __builtin_amdgcn_s_setprio(0);
  }
  const float* bias = (nb == 0) ? b1 : (nb == 1 ? b2 : b3);
#pragma unroll
  for (int mi = 0; mi < 4; ++mi)
#pragma unroll
    for (int ni = 0; ni < 4; ++ni) {
      float bv = bias[wn + ni * 16 + col];
#pragma unroll
      for (int r = 0; r < 4; ++r)
        oL[(wm + mi * 16 + quad * 4 + r) * 136 + wn + ni * 16 + col] = f2bs(acc[mi][ni][r] + bv);
    }
  __syncthreads();
  short* O = ((nb == 0) ? theta : (nb == 1) ? phi : gbuf) + ((size_t)b * 4096 + m0) * 128;
#pragma unroll
  for (int it = 0; it < 8; ++it) {
    int slot = it * 256 + tid;            // 2048 slots of 8 shorts
    int r = slot >> 4, cp = (slot & 15) * 8;
    *(bf16x8*)(O + (size_t)r * 128 + cp) = lds8(&oL[r * 136 + cp]);
  }
}

// ---------------- K2: denom (R2-proven config): 128-j tiles, counted vmcnt, delayed store ----
__global__ __launch_bounds__(256, 2) void k_denom(const short* __restrict__ theta,
                                                  const short* __restrict__ phi,
                                                  float* __restrict__ dpart) {
  __shared__ short phB[2][16384];   // [buf][4 ks][128 j][32 k]
  __shared__ float part[1024];      // [8][128]
  int tid = threadIdx.x;
  int ib = blockIdx.x, jc = blockIdx.y, b = blockIdx.z;
  int lane = tid & 63, wid = tid >> 6;
  int col = lane & 15, quad = lane >> 4;
  int sl = (col >> 1) & 3;
  int qs = (quad ^ sl) << 3;
  int wm = (wid >> 1) * 64, wn = (wid & 1) * 64;
  const short* T = theta + ((size_t)b * 4096 + ib * 128) * 128;
  const short* P = phi + ((size_t)b * 4096 + (size_t)jc * 1024) * 128;
  float* dbase = dpart + ((size_t)(b * 32 + ib)) * 4096 + jc * 1024;
  // theta [128][128] staged across both buffers, then to registers
  short* Lb = &phB[0][0];
#pragma unroll
  for (int ks = 0; ks < 4; ++ks) stage_chunk(Lb + ks * 8192, T + ks * 32, 128, tid);
  __syncthreads();
  bf16x8 ath[4][4];
#pragma unroll
  for (int ks = 0; ks < 4; ++ks)
#pragma unroll
    for (int mi = 0; mi < 4; ++mi)
      ath[ks][mi] = lds8(&Lb[ks * 8192 + (wm + mi * 16 + col) * 32 + qs]);
  __syncthreads();
  // prologue stage jt=0
#pragma unroll
  for (int ks = 0; ks < 4; ++ks) stage_chunk(&phB[0][0] + ks * 4096, P + ks * 32, 128, tid);
  float dval = 0.f;
  for (int jt = 0; jt < 8; ++jt) {
    int cur = jt & 1;
    ASM_WAIT_VM_LGKM(0);   // stage(jt) landed; prior-iter LDS reads + delayed store done
    ASM_BARRIER();
    if (jt > 0 && tid < 128) dbase[(jt - 1) * 128 + tid] = dval;  // store from jt-1 (hidden)
    if (jt < 7) {
      const short* Pn = P + (size_t)(jt + 1) * 128 * 128;
#pragma unroll
      for (int ks = 0; ks < 4; ++ks) stage_chunk(&phB[cur ^ 1][0] + ks * 4096, Pn + ks * 32, 128, tid);
    }
    f32x4 sacc[4][4];
    zero_acc(sacc);
#pragma unroll
    for (int ks = 0; ks < 4; ++ks) {
      bf16x8 bp[4];
#pragma unroll
      for (int ni = 0; ni < 4; ++ni) bp[ni] = lds8(&phB[cur][ks * 4096 + (wn + ni * 16 + col) * 32 + qs]);
      __builtin_amdgcn_s_setprio(1);
#pragma unroll
      for (int mi = 0; mi < 4; ++mi)
#pragma unroll
        for (int ni = 0; ni < 4; ++ni)
          sacc[mi][ni] = MFMA16(ath[ks][mi], bp[ni], sacc[mi][ni], 0, 0, 0);
      __builtin_amdgcn_s_setprio(0);
    }
#pragma unroll
    for (int ni = 0; ni < 4; ++ni) {
      float s = 0.f;
#pragma unroll
      for (int mi = 0; mi < 4; ++mi)
#pragma unroll
        for (int r = 0; r < 4; ++r) s += __expf(sacc[mi][ni][r]);
      part[((wid >> 1) * 4 + quad) * 128 + wn + ni * 16 + col] = s;
    }
    ASM_WAIT_LGKM();   // part visible; stage(jt+1) keeps flying
    ASM_BARRIER();
    if (tid < 128) {
      float d = 0.f;
#pragma unroll
      for (int q = 0; q < 8; ++q) d += part[q * 128 + tid];
      dval = d;
    }
  }
  if (tid < 128) dbase[7 * 128 + tid] = dval;
}

// ---------------- K3: denom reduce + g'[c][j] = g[j][c]/denom[j] (bf16) ----------------
__global__ __launch_bounds__(256) void k_fold(const short* __restrict__ gbuf,
                                              const float* __restrict__ dpart,
                                              short* __restrict__ gprime) {
  __shared__ float dinv[128];
  __shared__ short t[128 * 136];
  int tid = threadIdx.x;
  int jb = blockIdx.x, b = blockIdx.y;
  int j0 = jb * 128;
  if (tid < 128) {
    float d = 0.f;
    for (int ib = 0; ib < 32; ++ib) d += dpart[((size_t)(b * 32 + ib)) * 4096 + j0 + tid];
    dinv[tid] = 1.0f / d;
  }
  __syncthreads();
  const short* G = gbuf + ((size_t)b * 4096 + j0) * 128;
#pragma unroll
  for (int it = 0; it < 8; ++it) {
    int slot = it * 256 + tid;          // 2048 x 8 shorts
    int j = slot >> 4, c8 = (slot & 15) * 8;
    bf16x8 gv = *(const bf16x8*)(G + (size_t)j * 128 + c8);
    float di = dinv[j];
#pragma unroll
    for (int e = 0; e < 8; ++e) t[(c8 + e) * 136 + j] = f2bs(bs2f(gv[e]) * di);
  }
  __syncthreads();
  short* GP = gprime + (size_t)b * 128 * 4096 + j0;
#pragma unroll
  for (int it = 0; it < 8; ++it) {
    int slot = it * 256 + tid;
    int c = slot >> 4, j8 = (slot & 15) * 8;
    *(bf16x8*)(GP + (size_t)c * 4096 + j8) = *(const bf16x8*)&t[c * 136 + j8];
  }
}

// ---------------- K4: fused S^T + exp + PV, KVBLK=32, 40 KB LDS -> 4 blocks/CU ----------------
// Block: 128 i x 512 j (16 jt of 32 j).  LDS map (shorts): ph[0]=0, ph[1]=4096,
// gp[0]=8192, gp[1]=12288, P=16384..20479.  4 independent barrier domains per CU.
// Per-j LDS traffic identical to the 64-j version; only domain count changes.
__global__ __launch_bounds__(256, 4) void k_attn_pv(const short* __restrict__ theta,
                                                    const short* __restrict__ phi,
                                                    const short* __restrict__ gprime,
                                                    short* __restrict__ ypart) {
  __shared__ short L[20480];   // 40 KB -> 4 blocks/CU
  int tid = threadIdx.x;
  int ib = blockIdx.x, jc = blockIdx.y, b = blockIdx.z;
  int lane = tid & 63, wid = tid >> 6;
  int col = lane & 15, quad = lane >> 4;
  int sl = (col >> 1) & 3;
  int qs = (quad ^ sl) << 3;   // swizzled granule offset for fragment reads
  int wm = (wid >> 1) * 64;    // i-half
  int cj = wid & 1;            // 16-j slice (S) / 64-c half (PV)
  int wnV = cj * 64;
  const short* T = theta + ((size_t)b * 4096 + ib * 128) * 128;
  const short* PH = phi + ((size_t)b * 4096 + (size_t)jc * 512) * 128;
  const short* GP = gprime + (size_t)b * 128 * 4096 + jc * 512;
  short* pP = L + 16384;
  // theta [128 i][128 k] staged into L[0..16383] (transient), then to registers
#pragma unroll
  for (int ks = 0; ks < 4; ++ks) stage_chunk(L + ks * 4096, T + ks * 32, 128, tid);
  __syncthreads();
  bf16x8 ath[4][4];
#pragma unroll
  for (int ks = 0; ks < 4; ++ks)
#pragma unroll
    for (int mi = 0; mi < 4; ++mi)
      ath[ks][mi] = lds8(&L[ks * 4096 + (wm + mi * 16 + col) * 32 + qs]);
  __syncthreads();
  // prologue: stage jt=0 (phi into ph[0], g' into gp[0])
  stage_phi32(L, PH, tid);
  stage_chunk(L + 8192, GP, 4096, tid);
  f32x4 accy[4][4];
  zero_acc(accy);
  int qh = quad >> 1, ql = (quad & 1) << 2;   // P-write: granule low bit / 8B half (shorts)
  for (int jt = 0; jt < 16; ++jt) {
    int cur = jt & 1;
    short* phc = L + cur * 4096;
    short* phn = L + (cur ^ 1) * 4096;
    short* gpc = L + 8192 + cur * 4096;
    short* gpn = L + 8192 + (cur ^ 1) * 4096;
    __syncthreads();   // stage(jt) complete; prior-iter LDS reads done
    if (jt < 15) {     // prefetch phi(jt+1) — overlaps S phase
      stage_phi32(phn, PH + (size_t)(jt + 1) * 32 * 128, tid);
    }
    // S^T = phi . theta^T  (m = j 32 [wave: 16], n = i 128 [wave: 64], K=128)
    f32x4 st[4];
#pragma unroll
    for (int ni = 0; ni < 4; ++ni) st[ni] = (f32x4){0.f, 0.f, 0.f, 0.f};
#pragma unroll
    for (int ks = 0; ks < 4; ++ks) {
      bf16x8 bp = lds8(&phc[ks * 1024 + (cj * 16 + col) * 32 + qs]);
      __builtin_amdgcn_s_setprio(1);
#pragma unroll
      for (int ni = 0; ni < 4; ++ni)
        st[ni] = MFMA16(bp, ath[ks][ni], st[ni], 0, 0, 0);
      __builtin_amdgcn_s_setprio(0);
    }
    // exp -> P[i 128][j 32] bf16; rows 64B, 16B-granule XOR-swizzled by ((i>>1)&3) = sl
    // j = cj*16 + quad*4 + r -> granule cj*2+qh, within-granule offset ql+r
#pragma unroll
    for (int ni = 0; ni < 4; ++ni) {
      int i = wm + ni * 16 + col;
      bf16x4 p4;
#pragma unroll
      for (int r = 0; r < 4; ++r) p4[r] = f2bs(__expf(st[ni][r]));
      *(bf16x4*)&pP[i * 32 + (((cj * 2 + qh) ^ sl) << 3) + ql] = p4;
    }
    __syncthreads();   // P visible (drains phi prefetch too)
    if (jt < 15) {     // prefetch g'(jt+1) — overlaps PV phase
      stage_chunk(gpn, GP + (jt + 1) * 32, 4096, tid);
    }
    // Y += P . g'^T  (m = i 128 [wave: 64], n = c 128 [wave: 64], K=32)
    bf16x8 ap[4], bg[4];
#pragma unroll
    for (int mi = 0; mi < 4; ++mi)
      ap[mi] = lds8(&pP[(wm + mi * 16 + col) * 32 + qs]);
#pragma unroll
    for (int ni = 0; ni < 4; ++ni)
      bg[ni] = lds8(&gpc[(wnV + ni * 16 + col) * 32 + qs]);
    __builtin_amdgcn_s_setprio(1);
#pragma unroll
    for (int mi = 0; mi < 4; ++mi)
#pragma unroll
      for (int ni = 0; ni < 4; ++ni)
        accy[mi][ni] = MFMA16(ap[mi], bg[ni], accy[mi][ni], 0, 0, 0);
    __builtin_amdgcn_s_setprio(0);
  }
  // epilogue: bf16 partial, repacked via L[0..8191] (two 64-row halves), 16 B stores
  short* eb = L;
  short* Yp = ypart + ((size_t)(jc * 4 + b) * 4096 + (size_t)ib * 128) * 128;
#pragma unroll
  for (int half = 0; half < 2; ++half) {
    __syncthreads();
    if ((wid >> 1) == half) {
#pragma unroll
      for (int mi = 0; mi < 4; ++mi)
#pragma unroll
        for (int ni = 0; ni < 4; ++ni)
#pragma unroll
          for (int r = 0; r < 4; ++r)
            eb[(mi * 16 + quad * 4 + r) * 128 + wnV + ni * 16 + col] = f2bs(accy[mi][ni][r]);
    }
    __syncthreads();
#pragma unroll
    for (int it = 0; it < 4; ++it) {
      int slot = it * 256 + tid;        // 1024 slots of 8 shorts over [64][128]
      int r = slot >> 4, c8 = (slot & 15) * 8;
      *(bf16x8*)(Yp + (size_t)(half * 64 + r) * 128 + c8) = lds8(&eb[r * 128 + c8]);
    }
  }
}

// ---------------- K5: out[o][i] = w4 . (sum of 8 bf16 ypart partials) + b4 + x ----------------
__global__ __launch_bounds__(256) void k_out(const short* __restrict__ ypart,
                                             const float* __restrict__ w4,
                                             const float* __restrict__ b4,
                                             const float* __restrict__ x,
                                             float* __restrict__ out) {
  __shared__ short wL[4 * 4096];   // [ksc][o][32c], 16B-granule swizzled
  __shared__ short yL[4 * 4096];   // [ksc][i][32c], 16B-granule swizzled
  __shared__ float bLs[128];
  int tid = threadIdx.x;
  int ibk = blockIdx.x, ob = blockIdx.y, b = blockIdx.z;
  int o0 = ob * 128, i0 = ibk * 128;
  int lane = tid & 63, wid = tid >> 6;
  int col = lane & 15, quad = lane >> 4;
  int sl = (col >> 1) & 3;
  int qsw = (quad ^ sl) << 3;
  int wm = (wid >> 1) * 64, wn = (wid & 1) * 64;
#pragma unroll
  for (int it = 0; it < 16; ++it) {
    int slot = it * 256 + tid;          // 4096 float4 slots over w4 [128][128]
    int r = slot >> 5, c4 = (slot & 31) * 4;
    int ks = c4 >> 5, cr = c4 & 31;
    f32x4 wv = *(const f32x4*)(w4 + (size_t)(o0 + r) * 128 + c4);
    bf16x4 wp;
#pragma unroll
    for (int e = 0; e < 4; ++e) wp[e] = f2bs(wv[e]);
    *(bf16x4*)&wL[ks * 4096 + r * 32 + ((((cr >> 3) ^ ((r >> 1) & 3)) << 3) | (cr & 4))] = wp;
  }
#pragma unroll
  for (int it = 0; it < 8; ++it) {
    int slot = it * 256 + tid;          // 2048 slots of 8 over y [128][128]
    int r = slot >> 4, c8 = (slot & 15) * 8;
    int ks = c8 >> 5, cr = c8 & 31;
    float a8[8];
#pragma unroll
    for (int e = 0; e < 8; ++e) a8[e] = 0.f;
#pragma unroll
    for (int p = 0; p < 8; ++p) {
      bf16x8 v = *(const bf16x8*)(ypart + ((size_t)(p * 4 + b) * 4096 + i0 + r) * 128 + c8);
#pragma unroll
      for (int e = 0; e < 8; ++e) a8[e] += bs2f(v[e]);
    }
    bf16x8 yv;
#pragma unroll
    for (int e = 0; e < 8; ++e) yv[e] = f2bs(a8[e]);
    *(bf16x8*)&yL[ks * 4096 + r * 32 + (((cr >> 3) ^ ((r >> 1) & 3)) << 3)] = yv;
  }
  if (tid < 128) bLs[tid] = b4[o0 + tid];
  __syncthreads();
  f32x4 acc[4][4];
  zero_acc(acc);
#pragma unroll
  for (int ks = 0; ks < 4; ++ks) {
    bf16x8 af[4], bf_[4];
#pragma unroll
    for (int mi = 0; mi < 4; ++mi) af[mi] = lds8(&wL[ks * 4096 + (wm + mi * 16 + col) * 32 + qsw]);
#pragma unroll
    for (int ni = 0; ni < 4; ++ni) bf_[ni] = lds8(&yL[ks * 4096 + (wn + ni * 16 + col) * 32 + qsw]);
#pragma unroll
    for (int mi = 0; mi < 4; ++mi)
#pragma unroll
      for (int ni = 0; ni < 4; ++ni)
        acc[mi][ni] = MFMA16(af[mi], bf_[ni], acc[mi][ni], 0, 0, 0);
  }
  const float* X = x + ((size_t)b * 256 + o0) * 4096 + i0;
  float* O = out + ((size_t)b * 256 + o0) * 4096 + i0;
#pragma unroll
  for (int mi = 0; mi < 4; ++mi)
#pragma unroll
    for (int ni = 0; ni < 4; ++ni)
#pragma unroll
      for (int r = 0; r < 4; ++r) {
        int o = wm + mi * 16 + quad * 4 + r;
        int i = wn + ni * 16 + col;
        O[(size_t)o * 4096 + i] = acc[mi][ni][r] + X[(size_t)o * 4096 + i] + bLs[o];
      }
}

extern "C" void kernel_launch(void* const* d_in, const int* in_sizes, int n_in,
                              void* d_out, int out_size, void* d_ws, size_t ws_size,
                              hipStream_t stream) {
  const float* x  = (const float*)d_in[0];
  const float* w1 = (const float*)d_in[1];
  const float* b1 = (const float*)d_in[2];
  const float* w2 = (const float*)d_in[3];
  const float* b2 = (const float*)d_in[4];
  const float* w3 = (const float*)d_in[5];
  const float* b3 = (const float*)d_in[6];
  const float* w4 = (const float*)d_in[7];
  const float* b4 = (const float*)d_in[8];
  char* ws = (char*)d_ws;
  short* xt     = (short*)(ws + 0);          // 4*4096*256*2   = 8,388,608
  short* w123   = (short*)(ws + 8388608);    // 384*256*2      =   196,608
  short* theta  = (short*)(ws + 8585216);    // 4*4096*128*2   = 4,194,304
  short* phi    = (short*)(ws + 12779520);   // 4,194,304
  short* gbuf   = (short*)(ws + 16973824);   // 4,194,304
  short* gprime = (short*)(ws + 21168128);   // 4,194,304
  float* dpart  = (float*)(ws + 25362432);   // 4*32*4096*4    = 2,097,152
  short* ypart  = (short*)(ws + 27459584);   // 8*4*4096*128*2 = 33,554,432 (end 61,014,016)
  float* out    = (float*)d_out;
  (void)in_sizes; (void)n_in; (void)out_size; (void)ws_size;

  k_transpose_cast<<<dim3(64, 4, 4), dim3(256), 0, stream>>>(x, xt);
  k_cast_w<<<dim3(384), dim3(256), 0, stream>>>(w1, w2, w3, w123);
  k_proj<<<dim3(32, 3, 4), dim3(256), 0, stream>>>(xt, w123, b1, b2, b3, theta, phi, gbuf);
  k_denom<<<dim3(32, 4, 4), dim3(256), 0, stream>>>(theta, phi, dpart);
  k_fold<<<dim3(32, 4), dim3(256), 0, stream>>>(gbuf, dpart, gprime);
  k_attn_pv<<<dim3(32, 8, 4), dim3(256), 0, stream>>>(theta, phi, gprime, ypart);
  k_out<<<dim3(32, 2, 4), dim3(256), 0, stream>>>(ypart, w4, b4, x, out);
}

// Round 6
// 169.226 us; speedup vs baseline: 1.9322x; 1.9322x over previous
//
#include <hip/hip_runtime.h>

#define DEVI __device__ __forceinline__

typedef __attribute__((ext_vector_type(8))) short bf16x8;
typedef __attribute__((ext_vector_type(4))) short bf16x4;
typedef __attribute__((ext_vector_type(4))) float f32x4;

#define MFMA16 __builtin_amdgcn_mfma_f32_16x16x32_bf16

// counted waits + raw barrier (used in k_proj / k_denom only)
#define ASM_WAIT_VM_LGKM(n) asm volatile("s_waitcnt vmcnt(" #n ") lgkmcnt(0)" ::: "memory")
#define ASM_WAIT_LGKM() asm volatile("s_waitcnt lgkmcnt(0)" ::: "memory")
#define ASM_BARRIER() do { __builtin_amdgcn_s_barrier(); asm volatile("" ::: "memory"); } while (0)

DEVI short f2bs(float f) {  // fp32 -> bf16 bits, round-nearest-even
  union { float f; unsigned u; } v; v.f = f;
  unsigned r = v.u + 0x7fffu + ((v.u >> 16) & 1u);
  return (short)(r >> 16);
}
DEVI float bs2f(short s) {
  union { unsigned u; float f; } v; v.u = ((unsigned)(unsigned short)s) << 16;
  return v.f;
}

DEVI void gload_lds16(const short* g, short* lds) {
  __builtin_amdgcn_global_load_lds(
      (const __attribute__((address_space(1))) unsigned int*)g,
      (__attribute__((address_space(3))) unsigned int*)lds, 16, 0, 0);
}

// Staged tile layout: [row][32 shorts], 16B-granule XOR-swizzled: physical
// granule gp of row holds logical granule gp ^ ((row>>1)&3).  LDS dest stays
// linear (global_load_lds constraint); the GLOBAL source is inverse-permuted.
// Readers of logical granule q use physical q ^ ((row>>1)&3); for fragment
// reads (row = base16 + col) this folds to the per-lane constant (col>>1)&3.

// stage a [128 rows][32 k] bf16 chunk (8 KB). 2 instrs/thread (256 thr).
DEVI void stage_chunk(short* lds, const short* g, int ldg, int tid) {
#pragma unroll
  for (int it = 0; it < 2; ++it) {
    int slot = it * 256 + tid;          // 0..511
    int row  = slot >> 2;               // 4 granules per 64 B row
    int ko   = ((slot ^ (slot >> 3)) & 3) << 3;   // (g ^ ((row>>1)&3)) * 8
    gload_lds16(g + (size_t)row * ldg + ko, lds + slot * 8);
  }
}

// stage a [64 rows][32 k] bf16 chunk (4 KB). 1 instr/thread (256 thr).
DEVI void stage_chunk64(short* lds, const short* g, int ldg, int tid) {
  int row = tid >> 2;
  int ko  = ((tid ^ (tid >> 3)) & 3) << 3;
  gload_lds16(g + (size_t)row * ldg + ko, lds + tid * 8);
}

DEVI bf16x8 lds8(const short* p) { return *(const bf16x8*)p; }

DEVI void zero_acc(f32x4 (&a)[4][4]) {
  f32x4 z = {0.f, 0.f, 0.f, 0.f};
#pragma unroll
  for (int i = 0; i < 4; ++i)
#pragma unroll
    for (int j = 0; j < 4; ++j) a[i][j] = z;
}

// ---------------- K0: x [b][256][4096] fp32 -> xt [b][4096][256] bf16 ----------------
__global__ __launch_bounds__(256) void k_transpose_cast(const float* __restrict__ x,
                                                        short* __restrict__ xt) {
  __shared__ float t[64][65];
  int b = blockIdx.z;
  int c0 = blockIdx.y * 64;
  int p0 = blockIdx.x * 64;
  int tid = threadIdx.x;
  const float* xb = x + (size_t)b * 256 * 4096;
#pragma unroll
  for (int i = 0; i < 16; ++i) {
    int idx = i * 256 + tid;
    int c = idx >> 6, p = idx & 63;
    t[p][c] = xb[(size_t)(c0 + c) * 4096 + p0 + p];
  }
  __syncthreads();
  short* xtb = xt + ((size_t)b * 4096 + p0) * 256 + c0;
#pragma unroll
  for (int i = 0; i < 16; ++i) {
    int idx = i * 256 + tid;
    int p = idx >> 6, c = idx & 63;
    xtb[(size_t)p * 256 + c] = f2bs(t[p][c]);
  }
}

// ---------------- K0b: cast w1/w2/w3 to bf16 (concatenated [384][256]) ----------------
__global__ __launch_bounds__(256) void k_cast_w(const float* __restrict__ w1,
                                                const float* __restrict__ w2,
                                                const float* __restrict__ w3,
                                                short* __restrict__ w123) {
  int i = blockIdx.x * 256 + threadIdx.x;
  if (i < 384 * 256) {
    int r = i >> 8;
    const float* w = (r < 128) ? w1 : (r < 256 ? w2 : w3);
    w123[i] = f2bs(w[(size_t)(r & 127) * 256 + (i & 255)]);
  }
}

// ---------------- K1: projections. D[pix][ch] = xt . W^T + bias ----------------
// double-buffered staging + counted vmcnt (R2-proven)
__global__ __launch_bounds__(256) void k_proj(const short* __restrict__ xt,
                                              const short* __restrict__ w123,
                                              const float* __restrict__ b1,
                                              const float* __restrict__ b2,
                                              const float* __restrict__ b3,
                                              short* __restrict__ theta,
                                              short* __restrict__ phi,
                                              short* __restrict__ gbuf) {
  __shared__ short aL[2][4096];
  __shared__ short bL[2][4096];
  __shared__ short oL[128 * 136];
  int tid = threadIdx.x;
  int m0 = blockIdx.x * 128;   // pixel tile
  int nb = blockIdx.y;         // 0=theta 1=phi 2=g
  int b  = blockIdx.z;
  int lane = tid & 63, wid = tid >> 6;
  int col = lane & 15, quad = lane >> 4;
  int sl = (col >> 1) & 3;
  int qs = (quad ^ sl) << 3;   // swizzled granule offset (shorts)
  int wm = (wid >> 1) * 64, wn = (wid & 1) * 64;
  const short* A = xt + ((size_t)b * 4096 + m0) * 256;
  const short* B = w123 + (size_t)nb * 128 * 256;
  f32x4 acc[4][4];
  zero_acc(acc);
  // prologue: stage ks=0
  stage_chunk(&aL[0][0], A, 256, tid);
  stage_chunk(&bL[0][0], B, 256, tid);
  for (int ks = 0; ks < 8; ++ks) {
    int cur = ks & 1;
    ASM_WAIT_VM_LGKM(0);    // stage(ks) landed (only outstanding VMEM)
    ASM_BARRIER();
    if (ks < 7) {
      stage_chunk(&aL[cur ^ 1][0], A + (ks + 1) * 32, 256, tid);
      stage_chunk(&bL[cur ^ 1][0], B + (ks + 1) * 32, 256, tid);
    }
    bf16x8 af[4], bf_[4];
#pragma unroll
    for (int mi = 0; mi < 4; ++mi) af[mi] = lds8(&aL[cur][(wm + mi * 16 + col) * 32 + qs]);
#pragma unroll
    for (int ni = 0; ni < 4; ++ni) bf_[ni] = lds8(&bL[cur][(wn + ni * 16 + col) * 32 + qs]);
    __builtin_amdgcn_s_setprio(1);
#pragma unroll
    for (int mi = 0; mi < 4; ++mi)
#pragma unroll
      for (int ni = 0; ni < 4; ++ni)
        acc[mi][ni] = MFMA16(af[mi], bf_[ni], acc[mi][ni], 0, 0, 0);
    __builtin_amdgcn_s_setprio(0);
  }
  const float* bias = (nb == 0) ? b1 : (nb == 1 ? b2 : b3);
#pragma unroll
  for (int mi = 0; mi < 4; ++mi)
#pragma unroll
    for (int ni = 0; ni < 4; ++ni) {
      float bv = bias[wn + ni * 16 + col];
#pragma unroll
      for (int r = 0; r < 4; ++r)
        oL[(wm + mi * 16 + quad * 4 + r) * 136 + wn + ni * 16 + col] = f2bs(acc[mi][ni][r] + bv);
    }
  __syncthreads();
  short* O = ((nb == 0) ? theta : (nb == 1) ? phi : gbuf) + ((size_t)b * 4096 + m0) * 128;
#pragma unroll
  for (int it = 0; it < 8; ++it) {
    int slot = it * 256 + tid;            // 2048 slots of 8 shorts
    int r = slot >> 4, cp = (slot & 15) * 8;
    *(bf16x8*)(O + (size_t)r * 128 + cp) = lds8(&oL[r * 136 + cp]);
  }
}

// ---------------- K2: denom (R2-proven): 128-j tiles, counted vmcnt, delayed store ----------
__global__ __launch_bounds__(256, 2) void k_denom(const short* __restrict__ theta,
                                                  const short* __restrict__ phi,
                                                  float* __restrict__ dpart) {
  __shared__ short phB[2][16384];   // [buf][4 ks][128 j][32 k]
  __shared__ float part[1024];      // [8][128]
  int tid = threadIdx.x;
  int ib = blockIdx.x, jc = blockIdx.y, b = blockIdx.z;
  int lane = tid & 63, wid = tid >> 6;
  int col = lane & 15, quad = lane >> 4;
  int sl = (col >> 1) & 3;
  int qs = (quad ^ sl) << 3;
  int wm = (wid >> 1) * 64, wn = (wid & 1) * 64;
  const short* T = theta + ((size_t)b * 4096 + ib * 128) * 128;
  const short* P = phi + ((size_t)b * 4096 + (size_t)jc * 1024) * 128;
  float* dbase = dpart + ((size_t)(b * 32 + ib)) * 4096 + jc * 1024;
  // theta [128][128] staged across both buffers, then to registers
  short* Lb = &phB[0][0];
#pragma unroll
  for (int ks = 0; ks < 4; ++ks) stage_chunk(Lb + ks * 8192, T + ks * 32, 128, tid);
  __syncthreads();
  bf16x8 ath[4][4];
#pragma unroll
  for (int ks = 0; ks < 4; ++ks)
#pragma unroll
    for (int mi = 0; mi < 4; ++mi)
      ath[ks][mi] = lds8(&Lb[ks * 8192 + (wm + mi * 16 + col) * 32 + qs]);
  __syncthreads();
  // prologue stage jt=0
#pragma unroll
  for (int ks = 0; ks < 4; ++ks) stage_chunk(&phB[0][0] + ks * 4096, P + ks * 32, 128, tid);
  float dval = 0.f;
  for (int jt = 0; jt < 8; ++jt) {
    int cur = jt & 1;
    ASM_WAIT_VM_LGKM(0);   // stage(jt) landed; prior-iter LDS reads + delayed store done
    ASM_BARRIER();
    if (jt > 0 && tid < 128) dbase[(jt - 1) * 128 + tid] = dval;  // store from jt-1 (hidden)
    if (jt < 7) {
      const short* Pn = P + (size_t)(jt + 1) * 128 * 128;
#pragma unroll
      for (int ks = 0; ks < 4; ++ks) stage_chunk(&phB[cur ^ 1][0] + ks * 4096, Pn + ks * 32, 128, tid);
    }
    f32x4 sacc[4][4];
    zero_acc(sacc);
#pragma unroll
    for (int ks = 0; ks < 4; ++ks) {
      bf16x8 bp[4];
#pragma unroll
      for (int ni = 0; ni < 4; ++ni) bp[ni] = lds8(&phB[cur][ks * 4096 + (wn + ni * 16 + col) * 32 + qs]);
      __builtin_amdgcn_s_setprio(1);
#pragma unroll
      for (int mi = 0; mi < 4; ++mi)
#pragma unroll
        for (int ni = 0; ni < 4; ++ni)
          sacc[mi][ni] = MFMA16(ath[ks][mi], bp[ni], sacc[mi][ni], 0, 0, 0);
      __builtin_amdgcn_s_setprio(0);
    }
#pragma unroll
    for (int ni = 0; ni < 4; ++ni) {
      float s = 0.f;
#pragma unroll
      for (int mi = 0; mi < 4; ++mi)
#pragma unroll
        for (int r = 0; r < 4; ++r) s += __expf(sacc[mi][ni][r]);
      part[((wid >> 1) * 4 + quad) * 128 + wn + ni * 16 + col] = s;
    }
    ASM_WAIT_LGKM();   // part visible; stage(jt+1) keeps flying
    ASM_BARRIER();
    if (tid < 128) {
      float d = 0.f;
#pragma unroll
      for (int q = 0; q < 8; ++q) d += part[q * 128 + tid];
      dval = d;
    }
  }
  if (tid < 128) dbase[7 * 128 + tid] = dval;
}

// ---------------- K3: denom reduce + g'[c][j] = g[j][c]/denom[j] (bf16) ----------------
__global__ __launch_bounds__(256) void k_fold(const short* __restrict__ gbuf,
                                              const float* __restrict__ dpart,
                                              short* __restrict__ gprime) {
  __shared__ float dinv[128];
  __shared__ short t[128 * 136];
  int tid = threadIdx.x;
  int jb = blockIdx.x, b = blockIdx.y;
  int j0 = jb * 128;
  if (tid < 128) {
    float d = 0.f;
    for (int ib = 0; ib < 32; ++ib) d += dpart[((size_t)(b * 32 + ib)) * 4096 + j0 + tid];
    dinv[tid] = 1.0f / d;
  }
  __syncthreads();
  const short* G = gbuf + ((size_t)b * 4096 + j0) * 128;
#pragma unroll
  for (int it = 0; it < 8; ++it) {
    int slot = it * 256 + tid;          // 2048 x 8 shorts
    int j = slot >> 4, c8 = (slot & 15) * 8;
    bf16x8 gv = *(const bf16x8*)(G + (size_t)j * 128 + c8);
    float di = dinv[j];
#pragma unroll
    for (int e = 0; e < 8; ++e) t[(c8 + e) * 136 + j] = f2bs(bs2f(gv[e]) * di);
  }
  __syncthreads();
  short* GP = gprime + (size_t)b * 128 * 4096 + j0;
#pragma unroll
  for (int it = 0; it < 8; ++it) {
    int slot = it * 256 + tid;
    int c = slot >> 4, j8 = (slot & 15) * 8;
    *(bf16x8*)(GP + (size_t)c * 4096 + j8) = *(const bf16x8*)&t[c * 136 + j8];
  }
}

// ---------------- K4: fused S^T recompute + exp + PV (R1/R4-proven, best measured 43.8) ----
// LDS map (shorts): ph[0]=L+0 (8192), ph[1]=L+8192, gp[0]=L+16384, gp[1]=L+24576, P=L+32768 (8192)
// S computed TRANSPOSED (mfma(phi, theta)): lane's 4 acc rows = 4 consecutive j at
// fixed i -> exp/pack is 8x ds_write_b64 (bf16x4) instead of 32x ds_write_b16.
__global__ __launch_bounds__(256, 2) void k_attn_pv(const short* __restrict__ theta,
                                                    const short* __restrict__ phi,
                                                    const short* __restrict__ gprime,
                                                    short* __restrict__ ypart) {
  __shared__ short L[40960];   // 80 KB exactly -> 2 blocks/CU
  int tid = threadIdx.x;
  int ib = blockIdx.x, jc = blockIdx.y, b = blockIdx.z;
  int lane = tid & 63, wid = tid >> 6;
  int col = lane & 15, quad = lane >> 4;
  int sl = (col >> 1) & 3;
  int qs = (quad ^ sl) << 3;   // swizzled granule offset for fragment reads
  int wm = (wid >> 1) * 64;
  int cj = wid & 1;            // which 32-j half this wave owns in S^T
  int wnS = cj * 32;
  int wnV = cj * 64;           // PV phase: n = c (128)
  const short* T = theta + ((size_t)b * 4096 + ib * 128) * 128;
  const short* PH = phi + ((size_t)b * 4096 + (size_t)jc * 1024) * 128;
  const short* GP = gprime + (size_t)b * 128 * 4096 + jc * 1024;
  short* pP = L + 32768;
  // theta [128 i][128 k] staged into L[0..32767], then to registers
#pragma unroll
  for (int ks = 0; ks < 4; ++ks) stage_chunk(L + ks * 8192, T + ks * 32, 128, tid);
  __syncthreads();
  bf16x8 ath[4][4];
#pragma unroll
  for (int ks = 0; ks < 4; ++ks)
#pragma unroll
    for (int mi = 0; mi < 4; ++mi)
      ath[ks][mi] = lds8(&L[ks * 8192 + (wm + mi * 16 + col) * 32 + qs]);
  __syncthreads();
  // prologue: stage jt=0 (phi into ph[0], g' into gp[0])
#pragma unroll
  for (int ks = 0; ks < 4; ++ks) stage_chunk64(L + ks * 2048, PH + ks * 32, 128, tid);
#pragma unroll
  for (int jh = 0; jh < 2; ++jh) stage_chunk(L + 16384 + jh * 4096, GP + jh * 32, 4096, tid);
  f32x4 accy[4][4];
  zero_acc(accy);
  int qh = quad >> 1, ql = (quad & 1) << 2;   // P-write: granule low bit / 8B half (shorts)
  for (int jt = 0; jt < 16; ++jt) {
    int cur = jt & 1;
    short* phc = L + cur * 8192;
    short* phn = L + (cur ^ 1) * 8192;
    short* gpc = L + 16384 + cur * 8192;
    short* gpn = L + 16384 + (cur ^ 1) * 8192;
    __syncthreads();   // stage(jt) complete; prior-iter LDS reads done
    if (jt < 15) {     // prefetch phi(jt+1) — overlaps S phase
      const short* PHn = PH + (size_t)(jt + 1) * 64 * 128;
#pragma unroll
      for (int ks = 0; ks < 4; ++ks) stage_chunk64(phn + ks * 2048, PHn + ks * 32, 128, tid);
    }
    // S^T = phi . theta^T  (m = j 64 [wave: 32], n = i 128 [wave: 64], K=128)
    f32x4 st[2][4];
#pragma unroll
    for (int mj = 0; mj < 2; ++mj)
#pragma unroll
      for (int ni = 0; ni < 4; ++ni) st[mj][ni] = (f32x4){0.f, 0.f, 0.f, 0.f};
#pragma unroll
    for (int ks = 0; ks < 4; ++ks) {
      bf16x8 bp[2];
#pragma unroll
      for (int mj = 0; mj < 2; ++mj)
        bp[mj] = lds8(&phc[ks * 2048 + (wnS + mj * 16 + col) * 32 + qs]);
      __builtin_amdgcn_s_setprio(1);
#pragma unroll
      for (int mj = 0; mj < 2; ++mj)
#pragma unroll
        for (int ni = 0; ni < 4; ++ni)
          st[mj][ni] = MFMA16(bp[mj], ath[ks][ni], st[mj][ni], 0, 0, 0);
      __builtin_amdgcn_s_setprio(0);
    }
    // exp -> P[i][j] bf16; rows 64B, 16B-granule XOR-swizzled by ((i>>1)&3) = sl
#pragma unroll
    for (int mj = 0; mj < 2; ++mj)
#pragma unroll
      for (int ni = 0; ni < 4; ++ni) {
        int i = wm + ni * 16 + col;
        bf16x4 p4;
#pragma unroll
        for (int r = 0; r < 4; ++r) p4[r] = f2bs(__expf(st[mj][ni][r]));
        *(bf16x4*)&pP[cj * 4096 + i * 32 + ((((mj << 1) + qh) ^ sl) << 3) + ql] = p4;
      }
    __syncthreads();   // P visible (drains phi prefetch too)
    if (jt < 15) {     // prefetch g'(jt+1) — overlaps PV phase
      const short* GPn = GP + (jt + 1) * 64;
#pragma unroll
      for (int jh = 0; jh < 2; ++jh) stage_chunk(gpn + jh * 4096, GPn + jh * 32, 4096, tid);
    }
    // Y += P . g'^T  (m=i 128, n=c 128, K=64)
#pragma unroll
    for (int ks = 0; ks < 2; ++ks) {
      bf16x8 ap[4], bg[4];
#pragma unroll
      for (int mi = 0; mi < 4; ++mi)
        ap[mi] = lds8(&pP[ks * 4096 + (wm + mi * 16 + col) * 32 + qs]);
#pragma unroll
      for (int ni = 0; ni < 4; ++ni)
        bg[ni] = lds8(&gpc[ks * 4096 + (wnV + ni * 16 + col) * 32 + qs]);
      __builtin_amdgcn_s_setprio(1);
#pragma unroll
      for (int mi = 0; mi < 4; ++mi)
#pragma unroll
        for (int ni = 0; ni < 4; ++ni)
          accy[mi][ni] = MFMA16(ap[mi], bg[ni], accy[mi][ni], 0, 0, 0);
      __builtin_amdgcn_s_setprio(0);
    }
  }
  // epilogue: bf16 partial, repacked via pP (two 64-row halves), coalesced 16 B stores
  short* Yp = ypart + ((size_t)(jc * 4 + b) * 4096 + (size_t)ib * 128) * 128;
#pragma unroll
  for (int half = 0; half < 2; ++half) {
    __syncthreads();
    if ((wid >> 1) == half) {
#pragma unroll
      for (int mi = 0; mi < 4; ++mi)
#pragma unroll
        for (int ni = 0; ni < 4; ++ni)
#pragma unroll
          for (int r = 0; r < 4; ++r)
            pP[(mi * 16 + quad * 4 + r) * 128 + wnV + ni * 16 + col] = f2bs(accy[mi][ni][r]);
    }
    __syncthreads();
#pragma unroll
    for (int it = 0; it < 4; ++it) {
      int slot = it * 256 + tid;        // 1024 slots of 8 shorts over [64][128]
      int r = slot >> 4, c8 = (slot & 15) * 8;
      *(bf16x8*)(Yp + (size_t)(half * 64 + r) * 128 + c8) = lds8(&pP[r * 128 + c8]);
    }
  }
}

// ---------------- K5: out[o][i] = w4 . (sum of 4 bf16 ypart partials) + b4 + x ----------------
__global__ __launch_bounds__(256) void k_out(const short* __restrict__ ypart,
                                             const float* __restrict__ w4,
                                             const float* __restrict__ b4,
                                             const float* __restrict__ x,
                                             float* __restrict__ out) {
  __shared__ short wL[4 * 4096];   // [ksc][o][32c], 16B-granule swizzled
  __shared__ short yL[4 * 4096];   // [ksc][i][32c], 16B-granule swizzled
  __shared__ float bLs[128];
  int tid = threadIdx.x;
  int ibk = blockIdx.x, ob = blockIdx.y, b = blockIdx.z;
  int o0 = ob * 128, i0 = ibk * 128;
  int lane = tid & 63, wid = tid >> 6;
  int col = lane & 15, quad = lane >> 4;
  int sl = (col >> 1) & 3;
  int qsw = (quad ^ sl) << 3;
  int wm = (wid >> 1) * 64, wn = (wid & 1) * 64;
#pragma unroll
  for (int it = 0; it < 16; ++it) {
    int slot = it * 256 + tid;          // 4096 float4 slots over w4 [128][128]
    int r = slot >> 5, c4 = (slot & 31) * 4;
    int ks = c4 >> 5, cr = c4 & 31;
    f32x4 wv = *(const f32x4*)(w4 + (size_t)(o0 + r) * 128 + c4);
    bf16x4 wp;
#pragma unroll
    for (int e = 0; e < 4; ++e) wp[e] = f2bs(wv[e]);
    *(bf16x4*)&wL[ks * 4096 + r * 32 + ((((cr >> 3) ^ ((r >> 1) & 3)) << 3) | (cr & 4))] = wp;
  }
#pragma unroll
  for (int it = 0; it < 8; ++it) {
    int slot = it * 256 + tid;          // 2048 slots of 8 over y [128][128]
    int r = slot >> 4, c8 = (slot & 15) * 8;
    int ks = c8 >> 5, cr = c8 & 31;
    float a8[8];
#pragma unroll
    for (int e = 0; e < 8; ++e) a8[e] = 0.f;
#pragma unroll
    for (int p = 0; p < 4; ++p) {
      bf16x8 v = *(const bf16x8*)(ypart + ((size_t)(p * 4 + b) * 4096 + i0 + r) * 128 + c8);
#pragma unroll
      for (int e = 0; e < 8; ++e) a8[e] += bs2f(v[e]);
    }
    bf16x8 yv;
#pragma unroll
    for (int e = 0; e < 8; ++e) yv[e] = f2bs(a8[e]);
    *(bf16x8*)&yL[ks * 4096 + r * 32 + (((cr >> 3) ^ ((r >> 1) & 3)) << 3)] = yv;
  }
  if (tid < 128) bLs[tid] = b4[o0 + tid];
  __syncthreads();
  f32x4 acc[4][4];
  zero_acc(acc);
#pragma unroll
  for (int ks = 0; ks < 4; ++ks) {
    bf16x8 af[4], bf_[4];
#pragma unroll
    for (int mi = 0; mi < 4; ++mi) af[mi] = lds8(&wL[ks * 4096 + (wm + mi * 16 + col) * 32 + qsw]);
#pragma unroll
    for (int ni = 0; ni < 4; ++ni) bf_[ni] = lds8(&yL[ks * 4096 + (wn + ni * 16 + col) * 32 + qsw]);
#pragma unroll
    for (int mi = 0; mi < 4; ++mi)
#pragma unroll
      for (int ni = 0; ni < 4; ++ni)
        acc[mi][ni] = MFMA16(af[mi], bf_[ni], acc[mi][ni], 0, 0, 0);
  }
  const float* X = x + ((size_t)b * 256 + o0) * 4096 + i0;
  float* O = out + ((size_t)b * 256 + o0) * 4096 + i0;
#pragma unroll
  for (int mi = 0; mi < 4; ++mi)
#pragma unroll
    for (int ni = 0; ni < 4; ++ni)
#pragma unroll
      for (int r = 0; r < 4; ++r) {
        int o = wm + mi * 16 + quad * 4 + r;
        int i = wn + ni * 16 + col;
        O[(size_t)o * 4096 + i] = acc[mi][ni][r] + X[(size_t)o * 4096 + i] + bLs[o];
      }
}

extern "C" void kernel_launch(void* const* d_in, const int* in_sizes, int n_in,
                              void* d_out, int out_size, void* d_ws, size_t ws_size,
                              hipStream_t stream) {
  const float* x  = (const float*)d_in[0];
  const float* w1 = (const float*)d_in[1];
  const float* b1 = (const float*)d_in[2];
  const float* w2 = (const float*)d_in[3];
  const float* b2 = (const float*)d_in[4];
  const float* w3 = (const float*)d_in[5];
  const float* b3 = (const float*)d_in[6];
  const float* w4 = (const float*)d_in[7];
  const float* b4 = (const float*)d_in[8];
  char* ws = (char*)d_ws;
  short* xt     = (short*)(ws + 0);          // 4*4096*256*2   = 8,388,608
  short* w123   = (short*)(ws + 8388608);    // 384*256*2      =   196,608
  short* theta  = (short*)(ws + 8585216);    // 4*4096*128*2   = 4,194,304
  short* phi    = (short*)(ws + 12779520);   // 4,194,304
  short* gbuf   = (short*)(ws + 16973824);   // 4,194,304
  short* gprime = (short*)(ws + 21168128);   // 4,194,304
  float* dpart  = (float*)(ws + 25362432);   // 4*32*4096*4    = 2,097,152
  short* ypart  = (short*)(ws + 27459584);   // 4*4*4096*128*2 = 16,777,216 (end 44,236,800)
  float* out    = (float*)d_out;
  (void)in_sizes; (void)n_in; (void)out_size; (void)ws_size;

  k_transpose_cast<<<dim3(64, 4, 4), dim3(256), 0, stream>>>(x, xt);
  k_cast_w<<<dim3(384), dim3(256), 0, stream>>>(w1, w2, w3, w123);
  k_proj<<<dim3(32, 3, 4), dim3(256), 0, stream>>>(xt, w123, b1, b2, b3, theta, phi, gbuf);
  k_denom<<<dim3(32, 4, 4), dim3(256), 0, stream>>>(theta, phi, dpart);
  k_fold<<<dim3(32, 4), dim3(256), 0, stream>>>(gbuf, dpart, gprime);
  k_attn_pv<<<dim3(32, 4, 4), dim3(256), 0, stream>>>(theta, phi, gprime, ypart);
  k_out<<<dim3(32, 2, 4), dim3(256), 0, stream>>>(ypart, w4, b4, x, out);
}

// Round 7
// 167.115 us; speedup vs baseline: 1.9566x; 1.0126x over previous
//
#include <hip/hip_runtime.h>

#define DEVI __device__ __forceinline__

typedef __attribute__((ext_vector_type(8))) short bf16x8;
typedef __attribute__((ext_vector_type(4))) short bf16x4;
typedef __attribute__((ext_vector_type(4))) float f32x4;

#define MFMA16 __builtin_amdgcn_mfma_f32_16x16x32_bf16

// counted waits + raw barrier (used in k_proj / k_denom only)
#define ASM_WAIT_VM_LGKM(n) asm volatile("s_waitcnt vmcnt(" #n ") lgkmcnt(0)" ::: "memory")
#define ASM_WAIT_LGKM() asm volatile("s_waitcnt lgkmcnt(0)" ::: "memory")
#define ASM_BARRIER() do { __builtin_amdgcn_s_barrier(); asm volatile("" ::: "memory"); } while (0)

DEVI short f2bs(float f) {  // fp32 -> bf16 bits, round-nearest-even
  union { float f; unsigned u; } v; v.f = f;
  unsigned r = v.u + 0x7fffu + ((v.u >> 16) & 1u);
  return (short)(r >> 16);
}
DEVI float bs2f(short s) {
  union { unsigned u; float f; } v; v.u = ((unsigned)(unsigned short)s) << 16;
  return v.f;
}

DEVI void gload_lds16(const short* g, short* lds) {
  __builtin_amdgcn_global_load_lds(
      (const __attribute__((address_space(1))) unsigned int*)g,
      (__attribute__((address_space(3))) unsigned int*)lds, 16, 0, 0);
}

// Staged tile layout: [row][32 shorts], 16B-granule XOR-swizzled: physical
// granule gp of row holds logical granule gp ^ ((row>>1)&3).  LDS dest stays
// linear (global_load_lds constraint); the GLOBAL source is inverse-permuted.
// Readers of logical granule q use physical q ^ ((row>>1)&3); for fragment
// reads (row = base16 + col) this folds to the per-lane constant (col>>1)&3.

// stage a [128 rows][32 k] bf16 chunk (8 KB). 2 instrs/thread (256 thr).
DEVI void stage_chunk(short* lds, const short* g, int ldg, int tid) {
#pragma unroll
  for (int it = 0; it < 2; ++it) {
    int slot = it * 256 + tid;          // 0..511
    int row  = slot >> 2;               // 4 granules per 64 B row
    int ko   = ((slot ^ (slot >> 3)) & 3) << 3;   // (g ^ ((row>>1)&3)) * 8
    gload_lds16(g + (size_t)row * ldg + ko, lds + slot * 8);
  }
}

// stage a [64 rows][32 k] bf16 chunk (4 KB). 1 instr/thread (256 thr).
DEVI void stage_chunk64(short* lds, const short* g, int ldg, int tid) {
  int row = tid >> 2;
  int ko  = ((tid ^ (tid >> 3)) & 3) << 3;
  gload_lds16(g + (size_t)row * ldg + ko, lds + tid * 8);
}

DEVI bf16x8 lds8(const short* p) { return *(const bf16x8*)p; }

DEVI void zero_acc(f32x4 (&a)[4][4]) {
  f32x4 z = {0.f, 0.f, 0.f, 0.f};
#pragma unroll
  for (int i = 0; i < 4; ++i)
#pragma unroll
    for (int j = 0; j < 4; ++j) a[i][j] = z;
}

// ---------------- K0: x [b][256][4096] fp32 -> xt [b][4096][256] bf16 ----------------
__global__ __launch_bounds__(256) void k_transpose_cast(const float* __restrict__ x,
                                                        short* __restrict__ xt) {
  __shared__ float t[64][65];
  int b = blockIdx.z;
  int c0 = blockIdx.y * 64;
  int p0 = blockIdx.x * 64;
  int tid = threadIdx.x;
  const float* xb = x + (size_t)b * 256 * 4096;
#pragma unroll
  for (int i = 0; i < 16; ++i) {
    int idx = i * 256 + tid;
    int c = idx >> 6, p = idx & 63;
    t[p][c] = xb[(size_t)(c0 + c) * 4096 + p0 + p];
  }
  __syncthreads();
  short* xtb = xt + ((size_t)b * 4096 + p0) * 256 + c0;
#pragma unroll
  for (int i = 0; i < 16; ++i) {
    int idx = i * 256 + tid;
    int p = idx >> 6, c = idx & 63;
    xtb[(size_t)p * 256 + c] = f2bs(t[p][c]);
  }
}

// ---------------- K0b: cast w1/w2/w3 to bf16 (concatenated [384][256]) ----------------
__global__ __launch_bounds__(256) void k_cast_w(const float* __restrict__ w1,
                                                const float* __restrict__ w2,
                                                const float* __restrict__ w3,
                                                short* __restrict__ w123) {
  int i = blockIdx.x * 256 + threadIdx.x;
  if (i < 384 * 256) {
    int r = i >> 8;
    const float* w = (r < 128) ? w1 : (r < 256 ? w2 : w3);
    w123[i] = f2bs(w[(size_t)(r & 127) * 256 + (i & 255)]);
  }
}

// ---------------- K1: projections. D[pix][ch] = xt . W^T + bias ----------------
// double-buffered staging + counted vmcnt (R2-proven)
__global__ __launch_bounds__(256) void k_proj(const short* __restrict__ xt,
                                              const short* __restrict__ w123,
                                              const float* __restrict__ b1,
                                              const float* __restrict__ b2,
                                              const float* __restrict__ b3,
                                              short* __restrict__ theta,
                                              short* __restrict__ phi,
                                              short* __restrict__ gbuf) {
  __shared__ short aL[2][4096];
  __shared__ short bL[2][4096];
  __shared__ short oL[128 * 136];
  int tid = threadIdx.x;
  int m0 = blockIdx.x * 128;   // pixel tile
  int nb = blockIdx.y;         // 0=theta 1=phi 2=g
  int b  = blockIdx.z;
  int lane = tid & 63, wid = tid >> 6;
  int col = lane & 15, quad = lane >> 4;
  int sl = (col >> 1) & 3;
  int qs = (quad ^ sl) << 3;   // swizzled granule offset (shorts)
  int wm = (wid >> 1) * 64, wn = (wid & 1) * 64;
  const short* A = xt + ((size_t)b * 4096 + m0) * 256;
  const short* B = w123 + (size_t)nb * 128 * 256;
  f32x4 acc[4][4];
  zero_acc(acc);
  // prologue: stage ks=0
  stage_chunk(&aL[0][0], A, 256, tid);
  stage_chunk(&bL[0][0], B, 256, tid);
  for (int ks = 0; ks < 8; ++ks) {
    int cur = ks & 1;
    ASM_WAIT_VM_LGKM(0);    // stage(ks) landed (only outstanding VMEM)
    ASM_BARRIER();
    if (ks < 7) {
      stage_chunk(&aL[cur ^ 1][0], A + (ks + 1) * 32, 256, tid);
      stage_chunk(&bL[cur ^ 1][0], B + (ks + 1) * 32, 256, tid);
    }
    bf16x8 af[4], bf_[4];
#pragma unroll
    for (int mi = 0; mi < 4; ++mi) af[mi] = lds8(&aL[cur][(wm + mi * 16 + col) * 32 + qs]);
#pragma unroll
    for (int ni = 0; ni < 4; ++ni) bf_[ni] = lds8(&bL[cur][(wn + ni * 16 + col) * 32 + qs]);
    __builtin_amdgcn_s_setprio(1);
#pragma unroll
    for (int mi = 0; mi < 4; ++mi)
#pragma unroll
      for (int ni = 0; ni < 4; ++ni)
        acc[mi][ni] = MFMA16(af[mi], bf_[ni], acc[mi][ni], 0, 0, 0);
    __builtin_amdgcn_s_setprio(0);
  }
  const float* bias = (nb == 0) ? b1 : (nb == 1 ? b2 : b3);
#pragma unroll
  for (int mi = 0; mi < 4; ++mi)
#pragma unroll
    for (int ni = 0; ni < 4; ++ni) {
      float bv = bias[wn + ni * 16 + col];
#pragma unroll
      for (int r = 0; r < 4; ++r)
        oL[(wm + mi * 16 + quad * 4 + r) * 136 + wn + ni * 16 + col] = f2bs(acc[mi][ni][r] + bv);
    }
  __syncthreads();
  short* O = ((nb == 0) ? theta : (nb == 1) ? phi : gbuf) + ((size_t)b * 4096 + m0) * 128;
#pragma unroll
  for (int it = 0; it < 8; ++it) {
    int slot = it * 256 + tid;            // 2048 slots of 8 shorts
    int r = slot >> 4, cp = (slot & 15) * 8;
    *(bf16x8*)(O + (size_t)r * 128 + cp) = lds8(&oL[r * 136 + cp]);
  }
}

// ---------------- K2: denom (R2-proven): 128-j tiles, counted vmcnt, delayed store ----------
__global__ __launch_bounds__(256, 2) void k_denom(const short* __restrict__ theta,
                                                  const short* __restrict__ phi,
                                                  float* __restrict__ dpart) {
  __shared__ short phB[2][16384];   // [buf][4 ks][128 j][32 k]
  __shared__ float part[1024];      // [8][128]
  int tid = threadIdx.x;
  int ib = blockIdx.x, jc = blockIdx.y, b = blockIdx.z;
  int lane = tid & 63, wid = tid >> 6;
  int col = lane & 15, quad = lane >> 4;
  int sl = (col >> 1) & 3;
  int qs = (quad ^ sl) << 3;
  int wm = (wid >> 1) * 64, wn = (wid & 1) * 64;
  const short* T = theta + ((size_t)b * 4096 + ib * 128) * 128;
  const short* P = phi + ((size_t)b * 4096 + (size_t)jc * 1024) * 128;
  float* dbase = dpart + ((size_t)(b * 32 + ib)) * 4096 + jc * 1024;
  // theta [128][128] staged across both buffers, then to registers
  short* Lb = &phB[0][0];
#pragma unroll
  for (int ks = 0; ks < 4; ++ks) stage_chunk(Lb + ks * 8192, T + ks * 32, 128, tid);
  __syncthreads();
  bf16x8 ath[4][4];
#pragma unroll
  for (int ks = 0; ks < 4; ++ks)
#pragma unroll
    for (int mi = 0; mi < 4; ++mi)
      ath[ks][mi] = lds8(&Lb[ks * 8192 + (wm + mi * 16 + col) * 32 + qs]);
  __syncthreads();
  // prologue stage jt=0
#pragma unroll
  for (int ks = 0; ks < 4; ++ks) stage_chunk(&phB[0][0] + ks * 4096, P + ks * 32, 128, tid);
  float dval = 0.f;
  for (int jt = 0; jt < 8; ++jt) {
    int cur = jt & 1;
    ASM_WAIT_VM_LGKM(0);   // stage(jt) landed; prior-iter LDS reads + delayed store done
    ASM_BARRIER();
    if (jt > 0 && tid < 128) dbase[(jt - 1) * 128 + tid] = dval;  // store from jt-1 (hidden)
    if (jt < 7) {
      const short* Pn = P + (size_t)(jt + 1) * 128 * 128;
#pragma unroll
      for (int ks = 0; ks < 4; ++ks) stage_chunk(&phB[cur ^ 1][0] + ks * 4096, Pn + ks * 32, 128, tid);
    }
    f32x4 sacc[4][4];
    zero_acc(sacc);
#pragma unroll
    for (int ks = 0; ks < 4; ++ks) {
      bf16x8 bp[4];
#pragma unroll
      for (int ni = 0; ni < 4; ++ni) bp[ni] = lds8(&phB[cur][ks * 4096 + (wn + ni * 16 + col) * 32 + qs]);
      __builtin_amdgcn_s_setprio(1);
#pragma unroll
      for (int mi = 0; mi < 4; ++mi)
#pragma unroll
        for (int ni = 0; ni < 4; ++ni)
          sacc[mi][ni] = MFMA16(ath[ks][mi], bp[ni], sacc[mi][ni], 0, 0, 0);
      __builtin_amdgcn_s_setprio(0);
    }
#pragma unroll
    for (int ni = 0; ni < 4; ++ni) {
      float s = 0.f;
#pragma unroll
      for (int mi = 0; mi < 4; ++mi)
#pragma unroll
        for (int r = 0; r < 4; ++r) s += __expf(sacc[mi][ni][r]);
      part[((wid >> 1) * 4 + quad) * 128 + wn + ni * 16 + col] = s;
    }
    ASM_WAIT_LGKM();   // part visible; stage(jt+1) keeps flying
    ASM_BARRIER();
    if (tid < 128) {
      float d = 0.f;
#pragma unroll
      for (int q = 0; q < 8; ++q) d += part[q * 128 + tid];
      dval = d;
    }
  }
  if (tid < 128) dbase[7 * 128 + tid] = dval;
}

// ---------------- K3: denom reduce + g'[c][j] = g[j][c]/denom[j] (bf16) ----------------
__global__ __launch_bounds__(256) void k_fold(const short* __restrict__ gbuf,
                                              const float* __restrict__ dpart,
                                              short* __restrict__ gprime) {
  __shared__ float dinv[128];
  __shared__ short t[128 * 136];
  int tid = threadIdx.x;
  int jb = blockIdx.x, b = blockIdx.y;
  int j0 = jb * 128;
  if (tid < 128) {
    float d = 0.f;
    for (int ib = 0; ib < 32; ++ib) d += dpart[((size_t)(b * 32 + ib)) * 4096 + j0 + tid];
    dinv[tid] = 1.0f / d;
  }
  __syncthreads();
  const short* G = gbuf + ((size_t)b * 4096 + j0) * 128;
#pragma unroll
  for (int it = 0; it < 8; ++it) {
    int slot = it * 256 + tid;          // 2048 x 8 shorts
    int j = slot >> 4, c8 = (slot & 15) * 8;
    bf16x8 gv = *(const bf16x8*)(G + (size_t)j * 128 + c8);
    float di = dinv[j];
#pragma unroll
    for (int e = 0; e < 8; ++e) t[(c8 + e) * 136 + j] = f2bs(bs2f(gv[e]) * di);
  }
  __syncthreads();
  short* GP = gprime + (size_t)b * 128 * 4096 + j0;
#pragma unroll
  for (int it = 0; it < 8; ++it) {
    int slot = it * 256 + tid;
    int c = slot >> 4, j8 = (slot & 15) * 8;
    *(bf16x8*)(GP + (size_t)c * 4096 + j8) = *(const bf16x8*)&t[c * 136 + j8];
  }
}

// ---------------- K4: fused S^T + exp + PV, SOFTWARE-PIPELINED: S(jt+1) || PV(jt) ----------
// LDS map (shorts): ph[0]=L+0 (8192), ph[1]=L+8192, gp[0]=L+16384, gp[1]=L+24576, P=L+32768 (8192)
// Interval A: {stage phi(jt+2)->ph[jt&1], stage g'(jt+1)->gp[(jt+1)&1], S(jt+1) MFMA,
//              PV(jt) MFMA} — S and PV are independent -> MFMA pipe stays fed, exp off chain.
// Interval B (short): exp(st)->P.  Single P buffer is safe: PV reads of P(jt) sealed by B.
__global__ __launch_bounds__(256, 2) void k_attn_pv(const short* __restrict__ theta,
                                                    const short* __restrict__ phi,
                                                    const short* __restrict__ gprime,
                                                    short* __restrict__ ypart) {
  __shared__ short L[40960];   // 80 KB exactly -> 2 blocks/CU
  int tid = threadIdx.x;
  int ib = blockIdx.x, jc = blockIdx.y, b = blockIdx.z;
  int lane = tid & 63, wid = tid >> 6;
  int col = lane & 15, quad = lane >> 4;
  int sl = (col >> 1) & 3;
  int qs = (quad ^ sl) << 3;   // swizzled granule offset for fragment reads
  int wm = (wid >> 1) * 64;
  int cj = wid & 1;            // which 32-j half this wave owns in S^T
  int wnS = cj * 32;
  int wnV = cj * 64;           // PV phase: n = c (128)
  const short* T = theta + ((size_t)b * 4096 + ib * 128) * 128;
  const short* PH = phi + ((size_t)b * 4096 + (size_t)jc * 1024) * 128;
  const short* GP = gprime + (size_t)b * 128 * 4096 + jc * 1024;
  short* pP = L + 32768;
  // theta [128 i][128 k] staged into L[0..32767], then to registers
#pragma unroll
  for (int ks = 0; ks < 4; ++ks) stage_chunk(L + ks * 8192, T + ks * 32, 128, tid);
  __syncthreads();
  bf16x8 ath[4][4];
#pragma unroll
  for (int ks = 0; ks < 4; ++ks)
#pragma unroll
    for (int mi = 0; mi < 4; ++mi)
      ath[ks][mi] = lds8(&L[ks * 8192 + (wm + mi * 16 + col) * 32 + qs]);
  __syncthreads();
  int qh = quad >> 1, ql = (quad & 1) << 2;   // P-write: granule low bit / 8B half (shorts)
  f32x4 accy[4][4];
  zero_acc(accy);
  f32x4 st[2][4];
  // prologue: stage phi(0)->ph[0], g'(0)->gp[0]
#pragma unroll
  for (int ks = 0; ks < 4; ++ks) stage_chunk64(L + ks * 2048, PH + ks * 32, 128, tid);
#pragma unroll
  for (int jh = 0; jh < 2; ++jh) stage_chunk(L + 16384 + jh * 4096, GP + jh * 32, 4096, tid);
  __syncthreads();   // ph[0], gp[0] ready
  // S(0) from ph[0]
#pragma unroll
  for (int mj = 0; mj < 2; ++mj)
#pragma unroll
    for (int ni = 0; ni < 4; ++ni) st[mj][ni] = (f32x4){0.f, 0.f, 0.f, 0.f};
#pragma unroll
  for (int ks = 0; ks < 4; ++ks) {
    bf16x8 bp[2];
#pragma unroll
    for (int mj = 0; mj < 2; ++mj)
      bp[mj] = lds8(&L[ks * 2048 + (wnS + mj * 16 + col) * 32 + qs]);
#pragma unroll
    for (int mj = 0; mj < 2; ++mj)
#pragma unroll
      for (int ni = 0; ni < 4; ++ni)
        st[mj][ni] = MFMA16(bp[mj], ath[ks][ni], st[mj][ni], 0, 0, 0);
  }
  // stage phi(1)->ph[1]
#pragma unroll
  for (int ks = 0; ks < 4; ++ks) stage_chunk64(L + 8192 + ks * 2048, PH + 64 * 128 + ks * 32, 128, tid);
  __syncthreads();   // seal ph[0] reads (ph[1] also drains — harmless)
  // exp(S(0)) -> P
#pragma unroll
  for (int mj = 0; mj < 2; ++mj)
#pragma unroll
    for (int ni = 0; ni < 4; ++ni) {
      int i = wm + ni * 16 + col;
      bf16x4 p4;
#pragma unroll
      for (int r = 0; r < 4; ++r) p4[r] = f2bs(__expf(st[mj][ni][r]));
      *(bf16x4*)&pP[cj * 4096 + i * 32 + ((((mj << 1) + qh) ^ sl) << 3) + ql] = p4;
    }
  for (int jt = 0; jt < 16; ++jt) {
    int cur = jt & 1;
    short* phn = L + ((cur ^ 1) * 8192);          // ph[(jt+1)&1]: read by S(jt+1)
    short* phs = L + (cur * 8192);                // ph[jt&1]: stage target phi(jt+2)
    short* gpc = L + 16384 + cur * 8192;          // gp[jt&1]: read by PV(jt)
    short* gpn = L + 16384 + (cur ^ 1) * 8192;    // gp[(jt+1)&1]: stage target g'(jt+1)
    __syncthreads();   // A: P(jt) visible; ph[(jt+1)&1], gp[jt&1] staged-complete; prior reads sealed
    if (jt < 14) {     // stage phi(jt+2) — target not read this iter
#pragma unroll
      for (int ks = 0; ks < 4; ++ks)
        stage_chunk64(phs + ks * 2048, PH + (size_t)(jt + 2) * 64 * 128 + ks * 32, 128, tid);
    }
    if (jt < 15) {     // stage g'(jt+1) — target not read this iter
#pragma unroll
      for (int jh = 0; jh < 2; ++jh)
        stage_chunk(gpn + jh * 4096, GP + (jt + 1) * 64 + jh * 32, 4096, tid);
    }
    // S(jt+1) -> st (independent of PV below)
    if (jt < 15) {
#pragma unroll
      for (int mj = 0; mj < 2; ++mj)
#pragma unroll
        for (int ni = 0; ni < 4; ++ni) st[mj][ni] = (f32x4){0.f, 0.f, 0.f, 0.f};
#pragma unroll
      for (int ks = 0; ks < 4; ++ks) {
        bf16x8 bp[2];
#pragma unroll
        for (int mj = 0; mj < 2; ++mj)
          bp[mj] = lds8(&phn[ks * 2048 + (wnS + mj * 16 + col) * 32 + qs]);
        __builtin_amdgcn_s_setprio(1);
#pragma unroll
        for (int mj = 0; mj < 2; ++mj)
#pragma unroll
          for (int ni = 0; ni < 4; ++ni)
            st[mj][ni] = MFMA16(bp[mj], ath[ks][ni], st[mj][ni], 0, 0, 0);
        __builtin_amdgcn_s_setprio(0);
      }
    }
    // PV(jt): Y += P . g'^T  (m=i 128, n=c 128, K=64)
#pragma unroll
    for (int ks = 0; ks < 2; ++ks) {
      bf16x8 ap[4], bg[4];
#pragma unroll
      for (int mi = 0; mi < 4; ++mi)
        ap[mi] = lds8(&pP[ks * 4096 + (wm + mi * 16 + col) * 32 + qs]);
#pragma unroll
      for (int ni = 0; ni < 4; ++ni)
        bg[ni] = lds8(&gpc[ks * 4096 + (wnV + ni * 16 + col) * 32 + qs]);
      __builtin_amdgcn_s_setprio(1);
#pragma unroll
      for (int mi = 0; mi < 4; ++mi)
#pragma unroll
        for (int ni = 0; ni < 4; ++ni)
          accy[mi][ni] = MFMA16(ap[mi], bg[ni], accy[mi][ni], 0, 0, 0);
      __builtin_amdgcn_s_setprio(0);
    }
    __syncthreads();   // B: all PV reads of P(jt) sealed
    if (jt < 15) {     // exp(S(jt+1)) -> P (short interval)
#pragma unroll
      for (int mj = 0; mj < 2; ++mj)
#pragma unroll
        for (int ni = 0; ni < 4; ++ni) {
          int i = wm + ni * 16 + col;
          bf16x4 p4;
#pragma unroll
          for (int r = 0; r < 4; ++r) p4[r] = f2bs(__expf(st[mj][ni][r]));
          *(bf16x4*)&pP[cj * 4096 + i * 32 + ((((mj << 1) + qh) ^ sl) << 3) + ql] = p4;
        }
    }
  }
  // epilogue: bf16 partial, repacked via pP (two 64-row halves), coalesced 16 B stores
  short* Yp = ypart + ((size_t)(jc * 4 + b) * 4096 + (size_t)ib * 128) * 128;
#pragma unroll
  for (int half = 0; half < 2; ++half) {
    __syncthreads();
    if ((wid >> 1) == half) {
#pragma unroll
      for (int mi = 0; mi < 4; ++mi)
#pragma unroll
        for (int ni = 0; ni < 4; ++ni)
#pragma unroll
          for (int r = 0; r < 4; ++r)
            pP[(mi * 16 + quad * 4 + r) * 128 + wnV + ni * 16 + col] = f2bs(accy[mi][ni][r]);
    }
    __syncthreads();
#pragma unroll
    for (int it = 0; it < 4; ++it) {
      int slot = it * 256 + tid;        // 1024 slots of 8 shorts over [64][128]
      int r = slot >> 4, c8 = (slot & 15) * 8;
      *(bf16x8*)(Yp + (size_t)(half * 64 + r) * 128 + c8) = lds8(&pP[r * 128 + c8]);
    }
  }
}

// ---------------- K5: out[o][i] = w4 . (sum of 4 bf16 ypart partials) + b4 + x ----------------
__global__ __launch_bounds__(256) void k_out(const short* __restrict__ ypart,
                                             const float* __restrict__ w4,
                                             const float* __restrict__ b4,
                                             const float* __restrict__ x,
                                             float* __restrict__ out) {
  __shared__ short wL[4 * 4096];   // [ksc][o][32c], 16B-granule swizzled
  __shared__ short yL[4 * 4096];   // [ksc][i][32c], 16B-granule swizzled
  __shared__ float bLs[128];
  int tid = threadIdx.x;
  int ibk = blockIdx.x, ob = blockIdx.y, b = blockIdx.z;
  int o0 = ob * 128, i0 = ibk * 128;
  int lane = tid & 63, wid = tid >> 6;
  int col = lane & 15, quad = lane >> 4;
  int sl = (col >> 1) & 3;
  int qsw = (quad ^ sl) << 3;
  int wm = (wid >> 1) * 64, wn = (wid & 1) * 64;
#pragma unroll
  for (int it = 0; it < 16; ++it) {
    int slot = it * 256 + tid;          // 4096 float4 slots over w4 [128][128]
    int r = slot >> 5, c4 = (slot & 31) * 4;
    int ks = c4 >> 5, cr = c4 & 31;
    f32x4 wv = *(const f32x4*)(w4 + (size_t)(o0 + r) * 128 + c4);
    bf16x4 wp;
#pragma unroll
    for (int e = 0; e < 4; ++e) wp[e] = f2bs(wv[e]);
    *(bf16x4*)&wL[ks * 4096 + r * 32 + ((((cr >> 3) ^ ((r >> 1) & 3)) << 3) | (cr & 4))] = wp;
  }
#pragma unroll
  for (int it = 0; it < 8; ++it) {
    int slot = it * 256 + tid;          // 2048 slots of 8 over y [128][128]
    int r = slot >> 4, c8 = (slot & 15) * 8;
    int ks = c8 >> 5, cr = c8 & 31;
    float a8[8];
#pragma unroll
    for (int e = 0; e < 8; ++e) a8[e] = 0.f;
#pragma unroll
    for (int p = 0; p < 4; ++p) {
      bf16x8 v = *(const bf16x8*)(ypart + ((size_t)(p * 4 + b) * 4096 + i0 + r) * 128 + c8);
#pragma unroll
      for (int e = 0; e < 8; ++e) a8[e] += bs2f(v[e]);
    }
    bf16x8 yv;
#pragma unroll
    for (int e = 0; e < 8; ++e) yv[e] = f2bs(a8[e]);
    *(bf16x8*)&yL[ks * 4096 + r * 32 + (((cr >> 3) ^ ((r >> 1) & 3)) << 3)] = yv;
  }
  if (tid < 128) bLs[tid] = b4[o0 + tid];
  __syncthreads();
  f32x4 acc[4][4];
  zero_acc(acc);
#pragma unroll
  for (int ks = 0; ks < 4; ++ks) {
    bf16x8 af[4], bf_[4];
#pragma unroll
    for (int mi = 0; mi < 4; ++mi) af[mi] = lds8(&wL[ks * 4096 + (wm + mi * 16 + col) * 32 + qsw]);
#pragma unroll
    for (int ni = 0; ni < 4; ++ni) bf_[ni] = lds8(&yL[ks * 4096 + (wn + ni * 16 + col) * 32 + qsw]);
#pragma unroll
    for (int mi = 0; mi < 4; ++mi)
#pragma unroll
      for (int ni = 0; ni < 4; ++ni)
        acc[mi][ni] = MFMA16(af[mi], bf_[ni], acc[mi][ni], 0, 0, 0);
  }
  const float* X = x + ((size_t)b * 256 + o0) * 4096 + i0;
  float* O = out + ((size_t)b * 256 + o0) * 4096 + i0;
#pragma unroll
  for (int mi = 0; mi < 4; ++mi)
#pragma unroll
    for (int ni = 0; ni < 4; ++ni)
#pragma unroll
      for (int r = 0; r < 4; ++r) {
        int o = wm + mi * 16 + quad * 4 + r;
        int i = wn + ni * 16 + col;
        O[(size_t)o * 4096 + i] = acc[mi][ni][r] + X[(size_t)o * 4096 + i] + bLs[o];
      }
}

extern "C" void kernel_launch(void* const* d_in, const int* in_sizes, int n_in,
                              void* d_out, int out_size, void* d_ws, size_t ws_size,
                              hipStream_t stream) {
  const float* x  = (const float*)d_in[0];
  const float* w1 = (const float*)d_in[1];
  const float* b1 = (const float*)d_in[2];
  const float* w2 = (const float*)d_in[3];
  const float* b2 = (const float*)d_in[4];
  const float* w3 = (const float*)d_in[5];
  const float* b3 = (const float*)d_in[6];
  const float* w4 = (const float*)d_in[7];
  const float* b4 = (const float*)d_in[8];
  char* ws = (char*)d_ws;
  short* xt     = (short*)(ws + 0);          // 4*4096*256*2   = 8,388,608
  short* w123   = (short*)(ws + 8388608);    // 384*256*2      =   196,608
  short* theta  = (short*)(ws + 8585216);    // 4*4096*128*2   = 4,194,304
  short* phi    = (short*)(ws + 12779520);   // 4,194,304
  short* gbuf   = (short*)(ws + 16973824);   // 4,194,304
  short* gprime = (short*)(ws + 21168128);   // 4,194,304
  float* dpart  = (float*)(ws + 25362432);   // 4*32*4096*4    = 2,097,152
  short* ypart  = (short*)(ws + 27459584);   // 4*4*4096*128*2 = 16,777,216 (end 44,236,800)
  float* out    = (float*)d_out;
  (void)in_sizes; (void)n_in; (void)out_size; (void)ws_size;

  k_transpose_cast<<<dim3(64, 4, 4), dim3(256), 0, stream>>>(x, xt);
  k_cast_w<<<dim3(384), dim3(256), 0, stream>>>(w1, w2, w3, w123);
  k_proj<<<dim3(32, 3, 4), dim3(256), 0, stream>>>(xt, w123, b1, b2, b3, theta, phi, gbuf);
  k_denom<<<dim3(32, 4, 4), dim3(256), 0, stream>>>(theta, phi, dpart);
  k_fold<<<dim3(32, 4), dim3(256), 0, stream>>>(gbuf, dpart, gprime);
  k_attn_pv<<<dim3(32, 4, 4), dim3(256), 0, stream>>>(theta, phi, gprime, ypart);
  k_out<<<dim3(32, 2, 4), dim3(256), 0, stream>>>(ypart, w4, b4, x, out);
}